// Round 1
// baseline (2005.531 us; speedup 1.0000x reference)
//
#include <hip/hip_runtime.h>
#include <math.h>

// Problem constants (from reference setup_inputs)
#define B_DIM 2
#define L_DIM 2048
#define H_DIM 8
#define E_DIM 64
#define SCALE 0.125f            // 1/sqrt(64)
#define NTHREADS 256

// One block per (b,h,l) row of the attention matrix.
// Phase A: scores s<=l via float4 dots (q staged in LDS)
// Phase B: softmax (max + sum tree reductions in LDS)
// Phase C: coalesced SA row write (zeros above diagonal — d_out is poisoned)
// Phase D: PV accumulation: wave = s-phase (g), lane = e -> coalesced V reads
__global__ __launch_bounds__(NTHREADS)
void attn_row_kernel(const float* __restrict__ Q,
                     const float* __restrict__ K,
                     const float* __restrict__ Vv,
                     float* __restrict__ outV,    // [B,L,H,E]
                     float* __restrict__ outSA)   // [B,H,L,S]
{
    __shared__ float q_s[E_DIM];          // 256 B
    __shared__ float sc[L_DIM];           // 8 KB: scores -> exp(p)
    __shared__ float red[NTHREADS];       // 1 KB reductions
    __shared__ float vacc[4][E_DIM];      // 1 KB PV partials

    const int bid = blockIdx.x;
    const int l  = bid & (L_DIM - 1);     // fastest: adjacent blocks share (b,h) -> K/V L2 reuse
    const int bh = bid >> 11;             // L=2048
    const int h  = bh & (H_DIM - 1);
    const int b  = bh >> 3;
    const int t  = threadIdx.x;

    // ---- load q row into LDS ----
    const size_t qbase = (((size_t)b * L_DIM + l) * H_DIM + h) * E_DIM;
    if (t < E_DIM) q_s[t] = Q[qbase + t];
    __syncthreads();

    // ---- Phase A: scores for s in [0, l] ----
    const size_t kvbase = ((size_t)b * L_DIM * H_DIM + h) * E_DIM;  // + s*H*E
    float lmax = -INFINITY;
    for (int s = t; s <= l; s += NTHREADS) {
        const float4* kp = (const float4*)(K + kvbase + (size_t)s * (H_DIM * E_DIM));
        const float4* qp = (const float4*)q_s;
        float acc = 0.f;
#pragma unroll
        for (int i = 0; i < E_DIM / 4; ++i) {
            float4 kv = kp[i];
            float4 qv = qp[i];   // same address across lanes -> LDS broadcast
            acc += qv.x * kv.x + qv.y * kv.y + qv.z * kv.z + qv.w * kv.w;
        }
        acc *= SCALE;
        sc[s] = acc;
        lmax = fmaxf(lmax, acc);
    }

    // ---- Phase B1: block max ----
    red[t] = lmax;
    __syncthreads();
#pragma unroll
    for (int off = NTHREADS / 2; off > 0; off >>= 1) {
        if (t < off) red[t] = fmaxf(red[t], red[t + off]);
        __syncthreads();
    }
    const float m = red[0];
    __syncthreads();   // everyone has read red[0] before it is overwritten

    // ---- Phase B2: exp + block sum ----
    float lsum = 0.f;
    for (int s = t; s <= l; s += NTHREADS) {
        float p = __expf(sc[s] - m);
        sc[s] = p;
        lsum += p;
    }
    red[t] = lsum;
    __syncthreads();
#pragma unroll
    for (int off = NTHREADS / 2; off > 0; off >>= 1) {
        if (t < off) red[t] += red[t + off];
        __syncthreads();
    }
    const float inv_denom = 1.0f / red[0];
    __syncthreads();

    // ---- Phase C: write SA row (full L entries; zeros above diagonal) ----
    float* sa_row = outSA + (((size_t)b * H_DIM + h) * L_DIM + l) * (size_t)L_DIM;
    for (int s = t; s < L_DIM; s += NTHREADS) {
        sa_row[s] = (s <= l) ? sc[s] * inv_denom : 0.0f;
    }

    // ---- Phase D: V[b,l,h,:] = sum_s p[s] * Vv[b,s,h,:] * inv_denom ----
    const int e = t & (E_DIM - 1);
    const int g = t >> 6;                 // wave index 0..3 = s-phase
    float acc = 0.f;
    for (int s = g; s <= l; s += 4) {
        // lanes of a wave read 64 consecutive floats -> coalesced 256B
        acc += sc[s] * Vv[kvbase + (size_t)s * (H_DIM * E_DIM) + e];
    }
    vacc[g][e] = acc;
    __syncthreads();
    if (t < E_DIM) {
        float r = (vacc[0][t] + vacc[1][t] + vacc[2][t] + vacc[3][t]) * inv_denom;
        outV[qbase + t] = r;
    }
}

extern "C" void kernel_launch(void* const* d_in, const int* in_sizes, int n_in,
                              void* d_out, int out_size, void* d_ws, size_t ws_size,
                              hipStream_t stream) {
    const float* Q  = (const float*)d_in[0];
    const float* K  = (const float*)d_in[1];
    const float* Vv = (const float*)d_in[2];
    float* out   = (float*)d_out;
    float* outV  = out;                                        // [B,L,H,E] first
    float* outSA = out + (size_t)B_DIM * L_DIM * H_DIM * E_DIM; // then [B,H,L,S]

    dim3 grid(B_DIM * H_DIM * L_DIM);   // 32768 blocks
    dim3 block(NTHREADS);
    attn_row_kernel<<<grid, block, 0, stream>>>(Q, K, Vv, outV, outSA);
}

// Round 2
// 400.232 us; speedup vs baseline: 5.0109x; 5.0109x over previous
//
#include <hip/hip_runtime.h>
#include <math.h>

// B=2, L=2048, H=8, E=64; outputs: V [B,L,H,E] then SA [B,H,L,S], fp32.
#define L_DIM 2048
#define H_DIM 8
#define E_DIM 64
#define ROWSTRIDE (H_DIM * E_DIM)   // 512 floats between consecutive l
#define NT 256
#define LDP 72                       // padded LDS row stride in ushorts (144 B)

typedef __attribute__((ext_vector_type(8))) short short8;
typedef __attribute__((ext_vector_type(4))) float floatx4;

__device__ __forceinline__ unsigned short f2bf(float f) {
    unsigned int u = __builtin_bit_cast(unsigned int, f);
    u += 0x7fffu + ((u >> 16) & 1u);   // RNE
    return (unsigned short)(u >> 16);
}

__global__ __launch_bounds__(NT)
void attn_mfma_kernel(const float* __restrict__ Q,
                      const float* __restrict__ K,
                      const float* __restrict__ Vv,
                      float* __restrict__ outV,
                      float* __restrict__ outSA)
{
    __shared__ __align__(16) unsigned short Qs[64][LDP];
    __shared__ __align__(16) unsigned short Ks[64][LDP];
    __shared__ __align__(16) unsigned short Vt[64][LDP];  // transposed: Vt[e][s]
    __shared__ __align__(16) unsigned short Ps[64][LDP];

    const int t   = threadIdx.x;
    const int bid = blockIdx.x;
    // pair heavy/light q-tiles on adjacent block ids: (0,31),(1,30),...
    const int idx = bid & 31;
    const int qt  = (idx & 1) ? (31 - (idx >> 1)) : (idx >> 1);
    const int bh  = bid >> 5;
    const int h   = bh & 7;
    const int b   = bh >> 3;
    const int q0  = qt << 6;

    const int lane = t & 63;
    const int w    = t >> 6;        // wave id: rows 16w..16w+15
    const int l15  = lane & 15;
    const int quad = lane >> 4;

    const float* Qbase = Q  + ((size_t)b * L_DIM * ROWSTRIDE) + (size_t)h * E_DIM;
    const float* Kbase = K  + ((size_t)b * L_DIM * ROWSTRIDE) + (size_t)h * E_DIM;
    const float* Vbase = Vv + ((size_t)b * L_DIM * ROWSTRIDE) + (size_t)h * E_DIM;
    float* saBase = outSA + ((size_t)(b * H_DIM + h)) * L_DIM * L_DIM;

    const int sr = t >> 2;          // staging: row 0..63, 4 threads/row
    const int se = (t & 3) * 16;    // 16 consecutive elements per thread

    // ---- stage Q tile once, scale folded in (0.125 is exact in bf16) ----
    {
        const float* src = Qbase + (size_t)(q0 + sr) * ROWSTRIDE + se;
        float4 f0 = *(const float4*)(src + 0);
        float4 f1 = *(const float4*)(src + 4);
        float4 f2 = *(const float4*)(src + 8);
        float4 f3 = *(const float4*)(src + 12);
        union { unsigned short u[8]; short8 v; } p0, p1;
        p0.u[0]=f2bf(f0.x*0.125f); p0.u[1]=f2bf(f0.y*0.125f); p0.u[2]=f2bf(f0.z*0.125f); p0.u[3]=f2bf(f0.w*0.125f);
        p0.u[4]=f2bf(f1.x*0.125f); p0.u[5]=f2bf(f1.y*0.125f); p0.u[6]=f2bf(f1.z*0.125f); p0.u[7]=f2bf(f1.w*0.125f);
        p1.u[0]=f2bf(f2.x*0.125f); p1.u[1]=f2bf(f2.y*0.125f); p1.u[2]=f2bf(f2.z*0.125f); p1.u[3]=f2bf(f2.w*0.125f);
        p1.u[4]=f2bf(f3.x*0.125f); p1.u[5]=f2bf(f3.y*0.125f); p1.u[6]=f2bf(f3.z*0.125f); p1.u[7]=f2bf(f3.w*0.125f);
        *(short8*)&Qs[sr][se]     = p0.v;
        *(short8*)&Qs[sr][se + 8] = p1.v;
    }
    __syncthreads();

    // A-fragments of Q, constant for the whole kernel
    const short8 aQ0 = *(const short8*)&Qs[16 * w + l15][quad * 8];
    const short8 aQ1 = *(const short8*)&Qs[16 * w + l15][32 + quad * 8];

    float m_r[4], l_r[4];
#pragma unroll
    for (int r = 0; r < 4; ++r) { m_r[r] = -INFINITY; l_r[r] = 0.0f; }

    const int ntiles = qt + 1;

    // =================== PASS 1: row max & denom ===================
    for (int st = 0; st < ntiles; ++st) {
        const int s0 = st << 6;
        __syncthreads();   // protect Ks from previous iteration's readers
        {
            const float* src = Kbase + (size_t)(s0 + sr) * ROWSTRIDE + se;
            float4 f0 = *(const float4*)(src + 0);
            float4 f1 = *(const float4*)(src + 4);
            float4 f2 = *(const float4*)(src + 8);
            float4 f3 = *(const float4*)(src + 12);
            union { unsigned short u[8]; short8 v; } p0, p1;
            p0.u[0]=f2bf(f0.x); p0.u[1]=f2bf(f0.y); p0.u[2]=f2bf(f0.z); p0.u[3]=f2bf(f0.w);
            p0.u[4]=f2bf(f1.x); p0.u[5]=f2bf(f1.y); p0.u[6]=f2bf(f1.z); p0.u[7]=f2bf(f1.w);
            p1.u[0]=f2bf(f2.x); p1.u[1]=f2bf(f2.y); p1.u[2]=f2bf(f2.z); p1.u[3]=f2bf(f2.w);
            p1.u[4]=f2bf(f3.x); p1.u[5]=f2bf(f3.y); p1.u[6]=f2bf(f3.z); p1.u[7]=f2bf(f3.w);
            *(short8*)&Ks[sr][se]     = p0.v;
            *(short8*)&Ks[sr][se + 8] = p1.v;
        }
        __syncthreads();

        floatx4 d[4];
#pragma unroll
        for (int j = 0; j < 4; ++j) {
            short8 b0 = *(const short8*)&Ks[16 * j + l15][quad * 8];
            short8 b1 = *(const short8*)&Ks[16 * j + l15][32 + quad * 8];
            floatx4 acc = {0.f, 0.f, 0.f, 0.f};
            acc = __builtin_amdgcn_mfma_f32_16x16x32_bf16(aQ0, b0, acc, 0, 0, 0);
            acc = __builtin_amdgcn_mfma_f32_16x16x32_bf16(aQ1, b1, acc, 0, 0, 0);
            d[j] = acc;
        }

        const bool diag = (st == qt);
#pragma unroll
        for (int r = 0; r < 4; ++r) {
            const int lrow = q0 + 16 * w + quad * 4 + r;
            float v0 = d[0][r], v1 = d[1][r], v2 = d[2][r], v3 = d[3][r];
            if (diag) {
                v0 = (s0 +  0 + l15 <= lrow) ? v0 : -INFINITY;
                v1 = (s0 + 16 + l15 <= lrow) ? v1 : -INFINITY;
                v2 = (s0 + 32 + l15 <= lrow) ? v2 : -INFINITY;
                v3 = (s0 + 48 + l15 <= lrow) ? v3 : -INFINITY;
            }
            float vm = fmaxf(fmaxf(v0, v1), fmaxf(v2, v3));
#pragma unroll
            for (int mk = 1; mk < 16; mk <<= 1) vm = fmaxf(vm, __shfl_xor(vm, mk));
            const float mnew = fmaxf(m_r[r], vm);
            float es = __expf(v0 - mnew) + __expf(v1 - mnew) +
                       __expf(v2 - mnew) + __expf(v3 - mnew);
#pragma unroll
            for (int mk = 1; mk < 16; mk <<= 1) es += __shfl_xor(es, mk);
            l_r[r] = l_r[r] * __expf(m_r[r] - mnew) + es;
            m_r[r] = mnew;
        }
    }

    float invl[4];
#pragma unroll
    for (int r = 0; r < 4; ++r) invl[r] = 1.0f / l_r[r];

    // =================== PASS 2: SA write + PV ===================
    floatx4 oacc[4];
#pragma unroll
    for (int j = 0; j < 4; ++j) oacc[j] = (floatx4){0.f, 0.f, 0.f, 0.f};

    for (int st = 0; st < ntiles; ++st) {
        const int s0 = st << 6;
        __syncthreads();
        {   // stage K
            const float* src = Kbase + (size_t)(s0 + sr) * ROWSTRIDE + se;
            float4 f0 = *(const float4*)(src + 0);
            float4 f1 = *(const float4*)(src + 4);
            float4 f2 = *(const float4*)(src + 8);
            float4 f3 = *(const float4*)(src + 12);
            union { unsigned short u[8]; short8 v; } p0, p1;
            p0.u[0]=f2bf(f0.x); p0.u[1]=f2bf(f0.y); p0.u[2]=f2bf(f0.z); p0.u[3]=f2bf(f0.w);
            p0.u[4]=f2bf(f1.x); p0.u[5]=f2bf(f1.y); p0.u[6]=f2bf(f1.z); p0.u[7]=f2bf(f1.w);
            p1.u[0]=f2bf(f2.x); p1.u[1]=f2bf(f2.y); p1.u[2]=f2bf(f2.z); p1.u[3]=f2bf(f2.w);
            p1.u[4]=f2bf(f3.x); p1.u[5]=f2bf(f3.y); p1.u[6]=f2bf(f3.z); p1.u[7]=f2bf(f3.w);
            *(short8*)&Ks[sr][se]     = p0.v;
            *(short8*)&Ks[sr][se + 8] = p1.v;
        }
        {   // stage V transposed: Vt[e][s]
            const float* src = Vbase + (size_t)(s0 + sr) * ROWSTRIDE + se;
            float4 f0 = *(const float4*)(src + 0);
            float4 f1 = *(const float4*)(src + 4);
            float4 f2 = *(const float4*)(src + 8);
            float4 f3 = *(const float4*)(src + 12);
            Vt[se +  0][sr] = f2bf(f0.x); Vt[se +  1][sr] = f2bf(f0.y);
            Vt[se +  2][sr] = f2bf(f0.z); Vt[se +  3][sr] = f2bf(f0.w);
            Vt[se +  4][sr] = f2bf(f1.x); Vt[se +  5][sr] = f2bf(f1.y);
            Vt[se +  6][sr] = f2bf(f1.z); Vt[se +  7][sr] = f2bf(f1.w);
            Vt[se +  8][sr] = f2bf(f2.x); Vt[se +  9][sr] = f2bf(f2.y);
            Vt[se + 10][sr] = f2bf(f2.z); Vt[se + 11][sr] = f2bf(f2.w);
            Vt[se + 12][sr] = f2bf(f3.x); Vt[se + 13][sr] = f2bf(f3.y);
            Vt[se + 14][sr] = f2bf(f3.z); Vt[se + 15][sr] = f2bf(f3.w);
        }
        __syncthreads();

        floatx4 d[4];
#pragma unroll
        for (int j = 0; j < 4; ++j) {
            short8 b0 = *(const short8*)&Ks[16 * j + l15][quad * 8];
            short8 b1 = *(const short8*)&Ks[16 * j + l15][32 + quad * 8];
            floatx4 acc = {0.f, 0.f, 0.f, 0.f};
            acc = __builtin_amdgcn_mfma_f32_16x16x32_bf16(aQ0, b0, acc, 0, 0, 0);
            acc = __builtin_amdgcn_mfma_f32_16x16x32_bf16(aQ1, b1, acc, 0, 0, 0);
            d[j] = acc;
        }

        const bool diag = (st == qt);
#pragma unroll
        for (int r = 0; r < 4; ++r) {
            const int lrow = q0 + 16 * w + quad * 4 + r;
            float* sap = saBase + (size_t)lrow * L_DIM + s0 + l15;
            const float mr = m_r[r], il = invl[r];
#pragma unroll
            for (int j = 0; j < 4; ++j) {
                float v = d[j][r];
                bool ok = !diag || (s0 + 16 * j + l15 <= lrow);
                float p = ok ? __expf(v - mr) * il : 0.0f;
                sap[16 * j] = p;                                 // SA write (fp32)
                Ps[16 * w + quad * 4 + r][16 * j + l15] = f2bf(p);
            }
        }

        // PV: O += P * V   (Ps rows are wave-private; lgkmcnt handled by compiler)
        short8 aP0 = *(const short8*)&Ps[16 * w + l15][quad * 8];
        short8 aP1 = *(const short8*)&Ps[16 * w + l15][32 + quad * 8];
#pragma unroll
        for (int j = 0; j < 4; ++j) {
            short8 bv0 = *(const short8*)&Vt[16 * j + l15][quad * 8];
            short8 bv1 = *(const short8*)&Vt[16 * j + l15][32 + quad * 8];
            oacc[j] = __builtin_amdgcn_mfma_f32_16x16x32_bf16(aP0, bv0, oacc[j], 0, 0, 0);
            oacc[j] = __builtin_amdgcn_mfma_f32_16x16x32_bf16(aP1, bv1, oacc[j], 0, 0, 0);
        }
    }

    // ---- write O ----
#pragma unroll
    for (int r = 0; r < 4; ++r) {
        const int lrow = q0 + 16 * w + quad * 4 + r;
        float* op = outV + ((size_t)b * L_DIM + lrow) * ROWSTRIDE + (size_t)h * E_DIM + l15;
#pragma unroll
        for (int j = 0; j < 4; ++j) op[16 * j] = oacc[j][r];
    }

    // ---- zero-fill SA above the diagonal tile ----
    {
        const int z0 = (qt + 1) << 6;
        float* rowp = saBase + (size_t)(q0 + sr) * L_DIM;
        const float4 zf = {0.f, 0.f, 0.f, 0.f};
        for (int s = z0 + (t & 3) * 4; s < L_DIM; s += 16)
            *(float4*)(rowp + s) = zf;
    }
}

extern "C" void kernel_launch(void* const* d_in, const int* in_sizes, int n_in,
                              void* d_out, int out_size, void* d_ws, size_t ws_size,
                              hipStream_t stream) {
    const float* Q  = (const float*)d_in[0];
    const float* K  = (const float*)d_in[1];
    const float* Vv = (const float*)d_in[2];
    float* out   = (float*)d_out;
    float* outV  = out;                                           // [B,L,H,E]
    float* outSA = out + (size_t)2 * L_DIM * H_DIM * E_DIM;       // [B,H,L,S]

    dim3 grid(2 * H_DIM * 32);   // 512 blocks: (b,h) x 32 q-tiles (pair-swizzled)
    dim3 block(NT);
    attn_mfma_kernel<<<grid, block, 0, stream>>>(Q, K, Vv, outV, outSA);
}

// Round 3
// 389.901 us; speedup vs baseline: 5.1437x; 1.0265x over previous
//
#include <hip/hip_runtime.h>
#include <math.h>

// B=2, L=2048, H=8, E=64. Outputs: V [B,L,H,E] then SA [B,H,L,S], fp32.
#define L_DIM 2048
#define H_DIM 8
#define ROWSTRIDE 512                 // H*E floats between consecutive l
#define NT 512
// 0.125 * log2(e): scores computed in log2 domain -> raw v_exp_f32 for softmax
#define QSCALE 0.18033688011112042f

typedef __attribute__((ext_vector_type(8))) short short8;
typedef __attribute__((ext_vector_type(4))) float floatx4;

__device__ __forceinline__ unsigned short f2bf(float f) {
    // round-half-up (2 VALU ops); ties differ from RNE by <=1 ulp bf16 — irrelevant vs threshold
    unsigned int u = __builtin_bit_cast(unsigned int, f);
    return (unsigned short)((u + 0x8000u) >> 16);
}

__device__ __forceinline__ float fexp2(float x) {
#if __has_builtin(__builtin_amdgcn_exp2f)
    return __builtin_amdgcn_exp2f(x);   // raw v_exp_f32
#else
    return exp2f(x);
#endif
}

// 512 threads = 8 waves = 2 s-groups of 4 waves. Each block owns 64 q-rows of
// one (b,h). Group g processes s-tiles g, g+2, ... (2 tiles per barrier pair).
// Pass 1: online m/l per row (group-partial, combined via LDS).
// Pass 2: recompute scores, write normalized SA, accumulate partial O via PV
// MFMA; partial O combined via LDS (reusing the Ks region).
__global__ __launch_bounds__(NT, 4)
void attn_mfma2(const float* __restrict__ Q, const float* __restrict__ K,
                const float* __restrict__ Vv, float* __restrict__ outV,
                float* __restrict__ outSA)
{
    __shared__ __align__(16) unsigned char smem[65536];
    unsigned short* Qs = (unsigned short*)(smem);            // [64][72] bf16
    unsigned short* Ks = (unsigned short*)(smem + 9216);     // [2][64][72]
    unsigned short* Vt = (unsigned short*)(smem + 27648);    // [2][64][72] (Vt[e][s])
    unsigned short* Ps = (unsigned short*)(smem + 46080);    // [2][64][72]
    float* Ml = (float*)(smem + 64512);                      // [2][64]
    float* Ll = (float*)(smem + 65024);                      // [2][64]
    float* Ob = (float*)(smem + 9216);                       // [64][65] fp32, overlaps Ks

    const int t   = threadIdx.x;
    const int g   = t >> 8;            // s-group
    const int u   = t & 255;           // index within group
    const int bid = blockIdx.x;
    const int idx = bid & 31;          // pair heavy/light q-tiles
    const int qt  = (idx & 1) ? (31 - (idx >> 1)) : (idx >> 1);
    const int bh  = bid >> 5;
    const int h   = bh & 7;
    const int b   = bh >> 3;
    const int q0  = qt << 6;

    const int lane = t & 63;
    const int wg   = (t >> 6) & 3;     // wave within group: rows 16wg..16wg+15
    const int l15  = lane & 15;
    const int quad = lane >> 4;

    const float* Qb = Q  + (size_t)b * L_DIM * ROWSTRIDE + h * 64;
    const float* Kb = K  + (size_t)b * L_DIM * ROWSTRIDE + h * 64;
    const float* Vb = Vv + (size_t)b * L_DIM * ROWSTRIDE + h * 64;
    float* saBase = outSA + (size_t)(b * H_DIM + h) * L_DIM * L_DIM;

    // ---- stage Q once (512 threads, 8 elems each), scale folded ----
    {
        const int sr = t >> 3, se = (t & 7) * 8;
        const float* src = Qb + (size_t)(q0 + sr) * ROWSTRIDE + se;
        float4 f0 = *(const float4*)(src);
        float4 f1 = *(const float4*)(src + 4);
        union { unsigned short us[8]; short8 v; } p;
        p.us[0] = f2bf(f0.x * QSCALE); p.us[1] = f2bf(f0.y * QSCALE);
        p.us[2] = f2bf(f0.z * QSCALE); p.us[3] = f2bf(f0.w * QSCALE);
        p.us[4] = f2bf(f1.x * QSCALE); p.us[5] = f2bf(f1.y * QSCALE);
        p.us[6] = f2bf(f1.z * QSCALE); p.us[7] = f2bf(f1.w * QSCALE);
        *(short8*)&Qs[sr * 72 + se] = p.v;
    }
    __syncthreads();

    const short8 aQ0 = *(const short8*)&Qs[(16 * wg + l15) * 72 + quad * 8];
    const short8 aQ1 = *(const short8*)&Qs[(16 * wg + l15) * 72 + 32 + quad * 8];

    const int ntiles = qt + 1;
    const int niter  = (ntiles + 1) >> 1;
    const int ksr = u >> 2, kse = (u & 3) * 16;   // staging: 4 threads/row, 16 elems
    unsigned short* myKs = Ks + g * 4608;
    unsigned short* myVt = Vt + g * 4608;
    unsigned short* myPs = Ps + g * 4608;

    float m_r[4], l_r[4];
#pragma unroll
    for (int r = 0; r < 4; ++r) { m_r[r] = -INFINITY; l_r[r] = 0.f; }

    // =================== PASS 1: row max & denom ===================
    for (int it = 0; it < niter; ++it) {
        const int st = 2 * it + g;
        const bool active = (st < ntiles);
        const int s0 = st << 6;
        __syncthreads();
        if (active) {
            const float* src = Kb + (size_t)(s0 + ksr) * ROWSTRIDE + kse;
            float4 f0 = *(const float4*)(src + 0);
            float4 f1 = *(const float4*)(src + 4);
            float4 f2 = *(const float4*)(src + 8);
            float4 f3 = *(const float4*)(src + 12);
            union { unsigned short us[8]; short8 v; } p0, p1;
            p0.us[0]=f2bf(f0.x); p0.us[1]=f2bf(f0.y); p0.us[2]=f2bf(f0.z); p0.us[3]=f2bf(f0.w);
            p0.us[4]=f2bf(f1.x); p0.us[5]=f2bf(f1.y); p0.us[6]=f2bf(f1.z); p0.us[7]=f2bf(f1.w);
            p1.us[0]=f2bf(f2.x); p1.us[1]=f2bf(f2.y); p1.us[2]=f2bf(f2.z); p1.us[3]=f2bf(f2.w);
            p1.us[4]=f2bf(f3.x); p1.us[5]=f2bf(f3.y); p1.us[6]=f2bf(f3.z); p1.us[7]=f2bf(f3.w);
            *(short8*)&myKs[ksr * 72 + kse]     = p0.v;
            *(short8*)&myKs[ksr * 72 + kse + 8] = p1.v;
        }
        __syncthreads();
        if (!active) continue;    // barrier counts stay uniform (both at loop top)

        floatx4 d[4];
#pragma unroll
        for (int j = 0; j < 4; ++j) {
            short8 b0 = *(const short8*)&myKs[(16 * j + l15) * 72 + quad * 8];
            short8 b1 = *(const short8*)&myKs[(16 * j + l15) * 72 + 32 + quad * 8];
            floatx4 acc = {0.f, 0.f, 0.f, 0.f};
            acc = __builtin_amdgcn_mfma_f32_16x16x32_bf16(aQ0, b0, acc, 0, 0, 0);
            acc = __builtin_amdgcn_mfma_f32_16x16x32_bf16(aQ1, b1, acc, 0, 0, 0);
            d[j] = acc;
        }
        const bool diag = (st == qt);
#pragma unroll
        for (int r = 0; r < 4; ++r) {
            const int lrow = q0 + 16 * wg + quad * 4 + r;
            float v0 = d[0][r], v1 = d[1][r], v2 = d[2][r], v3 = d[3][r];
            if (diag) {
                v0 = (s0 +  0 + l15 <= lrow) ? v0 : -INFINITY;
                v1 = (s0 + 16 + l15 <= lrow) ? v1 : -INFINITY;
                v2 = (s0 + 32 + l15 <= lrow) ? v2 : -INFINITY;
                v3 = (s0 + 48 + l15 <= lrow) ? v3 : -INFINITY;
            }
            float vm = fmaxf(fmaxf(v0, v1), fmaxf(v2, v3));
#pragma unroll
            for (int mk = 1; mk < 16; mk <<= 1) vm = fmaxf(vm, __shfl_xor(vm, mk));
            const float mnew = fmaxf(m_r[r], vm);
            float es = fexp2(v0 - mnew) + fexp2(v1 - mnew) +
                       fexp2(v2 - mnew) + fexp2(v3 - mnew);
#pragma unroll
            for (int mk = 1; mk < 16; mk <<= 1) es += __shfl_xor(es, mk);
            l_r[r] = l_r[r] * fexp2(m_r[r] - mnew) + es;
            m_r[r] = mnew;
        }
    }

    // ---- combine m/l across the two s-groups ----
    __syncthreads();
    if (l15 == 0) {
#pragma unroll
        for (int r = 0; r < 4; ++r) {
            const int row = 16 * wg + quad * 4 + r;
            Ml[g * 64 + row] = m_r[r];
            Ll[g * 64 + row] = l_r[r];
        }
    }
    __syncthreads();
    float mfin[4], invl[4];
#pragma unroll
    for (int r = 0; r < 4; ++r) {
        const int row = 16 * wg + quad * 4 + r;
        float m0 = Ml[row], m1 = Ml[64 + row];
        float l0 = Ll[row], l1 = Ll[64 + row];
        float mf = fmaxf(m0, m1);              // finite: group 0 always has >=1 tile
        float lf = l0 * fexp2(m0 - mf) + l1 * fexp2(m1 - mf);  // 0*0=0 for idle group
        mfin[r] = mf;
        invl[r] = 1.0f / lf;
    }

    // =================== PASS 2: SA write + PV ===================
    floatx4 oacc[4];
#pragma unroll
    for (int j = 0; j < 4; ++j) oacc[j] = (floatx4){0.f, 0.f, 0.f, 0.f};

    for (int it = 0; it < niter; ++it) {
        const int st = 2 * it + g;
        const bool active = (st < ntiles);
        const int s0 = st << 6;
        __syncthreads();
        if (active) {
            {   // stage K
                const float* src = Kb + (size_t)(s0 + ksr) * ROWSTRIDE + kse;
                float4 f0 = *(const float4*)(src + 0);
                float4 f1 = *(const float4*)(src + 4);
                float4 f2 = *(const float4*)(src + 8);
                float4 f3 = *(const float4*)(src + 12);
                union { unsigned short us[8]; short8 v; } p0, p1;
                p0.us[0]=f2bf(f0.x); p0.us[1]=f2bf(f0.y); p0.us[2]=f2bf(f0.z); p0.us[3]=f2bf(f0.w);
                p0.us[4]=f2bf(f1.x); p0.us[5]=f2bf(f1.y); p0.us[6]=f2bf(f1.z); p0.us[7]=f2bf(f1.w);
                p1.us[0]=f2bf(f2.x); p1.us[1]=f2bf(f2.y); p1.us[2]=f2bf(f2.z); p1.us[3]=f2bf(f2.w);
                p1.us[4]=f2bf(f3.x); p1.us[5]=f2bf(f3.y); p1.us[6]=f2bf(f3.z); p1.us[7]=f2bf(f3.w);
                *(short8*)&myKs[ksr * 72 + kse]     = p0.v;
                *(short8*)&myKs[ksr * 72 + kse + 8] = p1.v;
            }
            {   // stage V transposed: Vt[e][s]
                const float* src = Vb + (size_t)(s0 + ksr) * ROWSTRIDE + kse;
                float4 f0 = *(const float4*)(src + 0);
                float4 f1 = *(const float4*)(src + 4);
                float4 f2 = *(const float4*)(src + 8);
                float4 f3 = *(const float4*)(src + 12);
                myVt[(kse +  0) * 72 + ksr] = f2bf(f0.x);
                myVt[(kse +  1) * 72 + ksr] = f2bf(f0.y);
                myVt[(kse +  2) * 72 + ksr] = f2bf(f0.z);
                myVt[(kse +  3) * 72 + ksr] = f2bf(f0.w);
                myVt[(kse +  4) * 72 + ksr] = f2bf(f1.x);
                myVt[(kse +  5) * 72 + ksr] = f2bf(f1.y);
                myVt[(kse +  6) * 72 + ksr] = f2bf(f1.z);
                myVt[(kse +  7) * 72 + ksr] = f2bf(f1.w);
                myVt[(kse +  8) * 72 + ksr] = f2bf(f2.x);
                myVt[(kse +  9) * 72 + ksr] = f2bf(f2.y);
                myVt[(kse + 10) * 72 + ksr] = f2bf(f2.z);
                myVt[(kse + 11) * 72 + ksr] = f2bf(f2.w);
                myVt[(kse + 12) * 72 + ksr] = f2bf(f3.x);
                myVt[(kse + 13) * 72 + ksr] = f2bf(f3.y);
                myVt[(kse + 14) * 72 + ksr] = f2bf(f3.z);
                myVt[(kse + 15) * 72 + ksr] = f2bf(f3.w);
            }
        }
        __syncthreads();
        if (!active) continue;

        floatx4 d[4];
#pragma unroll
        for (int j = 0; j < 4; ++j) {
            short8 b0 = *(const short8*)&myKs[(16 * j + l15) * 72 + quad * 8];
            short8 b1 = *(const short8*)&myKs[(16 * j + l15) * 72 + 32 + quad * 8];
            floatx4 acc = {0.f, 0.f, 0.f, 0.f};
            acc = __builtin_amdgcn_mfma_f32_16x16x32_bf16(aQ0, b0, acc, 0, 0, 0);
            acc = __builtin_amdgcn_mfma_f32_16x16x32_bf16(aQ1, b1, acc, 0, 0, 0);
            d[j] = acc;
        }
        const bool diag = (st == qt);
#pragma unroll
        for (int r = 0; r < 4; ++r) {
            const int lrow = q0 + 16 * wg + quad * 4 + r;
            float* sap = saBase + (size_t)lrow * L_DIM + s0 + l15;
            const float mr = mfin[r], il = invl[r];
#pragma unroll
            for (int j = 0; j < 4; ++j) {
                float v = d[j][r];
                bool ok = !diag || (s0 + 16 * j + l15 <= lrow);
                float p = ok ? fexp2(v - mr) * il : 0.0f;
                sap[16 * j] = p;
                myPs[(16 * wg + quad * 4 + r) * 72 + 16 * j + l15] = f2bf(p);
            }
        }
        // PV: rows of myPs are wave-private; compiler's lgkmcnt covers the RAW
        short8 aP0 = *(const short8*)&myPs[(16 * wg + l15) * 72 + quad * 8];
        short8 aP1 = *(const short8*)&myPs[(16 * wg + l15) * 72 + 32 + quad * 8];
#pragma unroll
        for (int j = 0; j < 4; ++j) {
            short8 bv0 = *(const short8*)&myVt[(16 * j + l15) * 72 + quad * 8];
            short8 bv1 = *(const short8*)&myVt[(16 * j + l15) * 72 + 32 + quad * 8];
            oacc[j] = __builtin_amdgcn_mfma_f32_16x16x32_bf16(aP0, bv0, oacc[j], 0, 0, 0);
            oacc[j] = __builtin_amdgcn_mfma_f32_16x16x32_bf16(aP1, bv1, oacc[j], 0, 0, 0);
        }
    }

    // ---- combine partial O across groups (Ob overlaps Ks; safe after barrier) ----
    __syncthreads();
    if (g == 1) {
#pragma unroll
        for (int r = 0; r < 4; ++r) {
            const int row = 16 * wg + quad * 4 + r;
#pragma unroll
            for (int j = 0; j < 4; ++j)
                Ob[row * 65 + 16 * j + l15] = oacc[j][r];
        }
    }
    __syncthreads();
    if (g == 0) {
#pragma unroll
        for (int r = 0; r < 4; ++r) {
            const int row = 16 * wg + quad * 4 + r;
            float* op = outV + ((size_t)b * L_DIM + q0 + row) * ROWSTRIDE + h * 64 + l15;
#pragma unroll
            for (int j = 0; j < 4; ++j)
                op[16 * j] = oacc[j][r] + Ob[row * 65 + 16 * j + l15];
        }
    }

    // ---- zero-fill SA above the diagonal tile (d_out is poisoned) ----
    {
        const int z0 = ntiles << 6;
        const int zr = t >> 3;               // 64 rows, 8 threads/row
        float* rowp = saBase + (size_t)(q0 + zr) * L_DIM;
        const float4 zf = {0.f, 0.f, 0.f, 0.f};
        for (int s = z0 + (t & 7) * 4; s < L_DIM; s += 32)
            *(float4*)(rowp + s) = zf;
    }
}

extern "C" void kernel_launch(void* const* d_in, const int* in_sizes, int n_in,
                              void* d_out, int out_size, void* d_ws, size_t ws_size,
                              hipStream_t stream) {
    const float* Q  = (const float*)d_in[0];
    const float* K  = (const float*)d_in[1];
    const float* Vv = (const float*)d_in[2];
    float* out   = (float*)d_out;
    float* outV  = out;                                       // [B,L,H,E]
    float* outSA = out + (size_t)2 * L_DIM * H_DIM * 64;      // [B,H,L,S]

    dim3 grid(2 * H_DIM * 32);   // 512 blocks: (b,h) x 32 q-tiles (pair-swizzled)
    dim3 block(NT);
    attn_mfma2<<<grid, block, 0, stream>>>(Q, K, Vv, outV, outSA);
}